// Round 7
// baseline (691.834 us; speedup 1.0000x reference)
//
#include <hip/hip_runtime.h>
#include <hip/hip_bf16.h>
#include <cstdint>

#define AS_GLOBAL __attribute__((address_space(1)))
#define AS_LDS    __attribute__((address_space(3)))

typedef __attribute__((ext_vector_type(8))) short bf16x8;
typedef __attribute__((ext_vector_type(4))) float f32x4;

static __device__ __forceinline__ ushort f2bf(float x) {
    union { float f; uint32_t u; } c;
    c.f = x;
    uint32_t u = c.u;
    u += 0x7fffu + ((u >> 16) & 1u);   // RTNE
    return (ushort)(u >> 16);
}
static __device__ __forceinline__ float bf2f(ushort u) {
    union { uint32_t i; float f; } c;
    c.i = ((uint32_t)u) << 16;
    return c.f;
}

// async global->LDS, 16B/lane. Dest must be wave-uniform base + lane*16.
static __device__ __forceinline__ void gload_lds16(const void* g, void* l) {
    __builtin_amdgcn_global_load_lds(
        (const AS_GLOBAL uint32_t*)(uintptr_t)g,
        (AS_LDS uint32_t*)(uint32_t)(uintptr_t)l,
        16, 0, 0);
}

// ---------------- [K,N] fp32 -> [N,K] bf16 transpose ----------------
__global__ __launch_bounds__(256)
void transpose_to_bf16(const float* __restrict__ w, ushort* __restrict__ wt, int K, int N) {
    __shared__ float tile[32][33];
    int bn = blockIdx.x * 32;
    int bk = blockIdx.y * 32;
    int tx = threadIdx.x & 31, ty = threadIdx.x >> 5;
    #pragma unroll
    for (int i = 0; i < 32; i += 8)
        tile[ty + i][tx] = w[(size_t)(bk + ty + i) * N + bn + tx];
    __syncthreads();
    #pragma unroll
    for (int i = 0; i < 32; i += 8)
        wt[(size_t)(bn + ty + i) * K + bk + tx] = f2bf(tile[tx][ty + i]);
}

// =====================================================================
// 128x128 GEMM, 4 waves, BK=32, ~3 blocks/CU, ONE barrier per K-step.
// A reg-staged (fused fp32->bf16 or bf16) into DOUBLE-BUFFERED padded LDS;
// B via global_load_lds into XOR-slot LDS, 4-deep ring staged 2 ahead;
// counted vmcnt(2) per step; lgkmcnt(0) before every barrier (race-safe).
// C[M,1024] = A[M,1024] * Bt[1024,1024](bf16).
// EPI: 0=none 1=sigmoid 2=exp.  A_F32: A fp32.  OUT_BF: bf16 C.
// =====================================================================
template<int EPI, int A_F32, int OUT_BF>
__global__ __launch_bounds__(256)
void gemm128(const void* __restrict__ Av, const ushort* __restrict__ Bt,
             void* __restrict__ Cv) {
    constexpr int K = 1024, N = 1024;
    constexpr int ASTR = 40;               // A row stride in ushorts (80B)
    __shared__ ushort sA[2][128 * ASTR];   // 2 x 10 KB, padded, double-buffered
    __shared__ ushort sB[4][128 * 32];     // 4 x 8 KB, XOR-slot layout
    const int tid  = threadIdx.x;
    const int wid  = tid >> 6;
    const int lane = tid & 63;
    const int wr = wid >> 1, wc = wid & 1; // 2x2 waves of 64x64
    const int lr = lane & 15;
    const int kb = lane >> 4;              // 0..3 (logical k-slot)

    // XCD-locality swizzle: 2048 wgs = 8 xcds x 256; one XCD's consecutive
    // locals cycle bn (8 values) sharing an A-panel -> A fetched ~once/XCD L2.
    const int wg = blockIdx.x;
    const int xcd = wg & 7, local = wg >> 3;
    const int bm = xcd * 32 + (local >> 3);
    const int bn = local & 7;
    const int m0 = bm * 128, n0 = bn * 128;

    const float*  Af = (const float*)Av;
    const ushort* Ab = (const ushort*)Av;

    f32x4 acc[4][4] = {};
    float4 fa0, fa1, fa2, fa3;             // in-flight fp32 A (4 loads)
    bf16x8 av0, av1;                       // in-flight bf16 A (2 loads)
    const int arow = tid >> 1;             // 0..127
    const int ahalf = tid & 1;             // 16-elem half of the 32-wide row

    // ---- B staging: gload_lds, linear dest, pre-swizzled source ----
    // phys slot p of row r holds logical slot p ^ (r&3)
    auto stageB = [&](int tile, int buf) {
        ushort* dst = &sB[buf][0];
        const int kt0 = tile * 32;
        #pragma unroll
        for (int j = 0; j < 2; j++) {
            int c = j * 256 + tid;         // 16B chunk id, 512 total
            int r = c >> 2, p = c & 3;
            int s = p ^ (r & 3);
            gload_lds16(Bt + (size_t)(n0 + r) * K + kt0 + s * 8, dst + c * 8);
        }
    };
    // ---- A staging: global -> regs ----
    auto issueA = [&](int tile) {
        const int kt0 = tile * 32;
        if (A_F32) {
            const float* s = Af + (size_t)(m0 + arow) * K + kt0 + ahalf * 16;
            fa0 = *(const float4*)(s);      fa1 = *(const float4*)(s + 4);
            fa2 = *(const float4*)(s + 8);  fa3 = *(const float4*)(s + 12);
        } else {
            const ushort* s = Ab + (size_t)(m0 + arow) * K + kt0 + ahalf * 16;
            av0 = *(const bf16x8*)(s);
            av1 = *(const bf16x8*)(s + 8);
        }
    };
    // ---- A regs -> LDS (padded layout; balanced banks) ----
    auto writeA = [&](int tile) {
        ushort* d = &sA[tile & 1][arow * ASTR + ahalf * 16];
        if (A_F32) {
            bf16x8 lo, hi;
            lo[0]=(short)f2bf(fa0.x); lo[1]=(short)f2bf(fa0.y); lo[2]=(short)f2bf(fa0.z); lo[3]=(short)f2bf(fa0.w);
            lo[4]=(short)f2bf(fa1.x); lo[5]=(short)f2bf(fa1.y); lo[6]=(short)f2bf(fa1.z); lo[7]=(short)f2bf(fa1.w);
            hi[0]=(short)f2bf(fa2.x); hi[1]=(short)f2bf(fa2.y); hi[2]=(short)f2bf(fa2.z); hi[3]=(short)f2bf(fa2.w);
            hi[4]=(short)f2bf(fa3.x); hi[5]=(short)f2bf(fa3.y); hi[6]=(short)f2bf(fa3.z); hi[7]=(short)f2bf(fa3.w);
            *(bf16x8*)d = lo;
            *(bf16x8*)(d + 8) = hi;
        } else {
            *(bf16x8*)d = av0;
            *(bf16x8*)(d + 8) = av1;
        }
    };
    // ---- compute one BK=32 step from LDS ----
    auto compute = [&](int t) {
        const ushort* pA = &sA[t & 1][0];
        const ushort* pB = &sB[t & 3][0];
        bf16x8 af[4], bv[4];
        #pragma unroll
        for (int m = 0; m < 4; m++)
            af[m] = *(const bf16x8*)&pA[(wr * 64 + m * 16 + lr) * ASTR + kb * 8];
        #pragma unroll
        for (int n = 0; n < 4; n++)
            bv[n] = *(const bf16x8*)&pB[(wc * 64 + n * 16 + lr) * 32 + ((kb ^ (lr & 3))) * 8];
        #pragma unroll
        for (int m = 0; m < 4; m++)
            #pragma unroll
            for (int n = 0; n < 4; n++)
                acc[m][n] = __builtin_amdgcn_mfma_f32_16x16x32_bf16(af[m], bv[n], acc[m][n], 0, 0, 0);
    };

    // ---- prologue: A(0)->regs, B(0),B(1)->gload ----
    issueA(0);
    asm volatile("" ::: "memory");                     // pin A-loads before B-gloads
    stageB(0, 0);
    stageB(1, 1);
    asm volatile("s_waitcnt vmcnt(4)" ::: "memory");   // A(0) done; B0,B1 in flight
    writeA(0);                                         // sA[0] := tile 0
    asm volatile("s_waitcnt vmcnt(2)" ::: "memory");   // B(0) done; B1 in flight
    asm volatile("s_waitcnt lgkmcnt(0)" ::: "memory"); // writeA visible
    __builtin_amdgcn_s_barrier();
    asm volatile("" ::: "memory");

    // ---- main loop: 32 K-steps, ONE barrier each ----
    // queue invariant at step t's vmcnt(2): [B(t+1)x2, A(t+1), B(t+2)x2]
    //   -> drains B(t+1)+A(t+1), leaves B(t+2).
    // LDS safety: sA[(t+1)&1] written at t, last read at t-1 (completed by
    // t-1's lgkmcnt(0)+barrier); sB ring has >=2 barriers between reuse.
    for (int t = 0; t < 32; t++) {
        if (t < 31) issueA(t + 1);
        asm volatile("" ::: "memory");                 // keep A-loads ahead of B-gloads
        if (t < 30) stageB(t + 2, (t + 2) & 3);
        compute(t);
        if (t < 31) {
            if (t < 30) asm volatile("s_waitcnt vmcnt(2)" ::: "memory");
            else        asm volatile("s_waitcnt vmcnt(0)" ::: "memory");
            writeA(t + 1);                             // sA[(t+1)&1] := tile t+1
        }
        asm volatile("s_waitcnt lgkmcnt(0)" ::: "memory");  // reads+writes drained
        __builtin_amdgcn_s_barrier();
        asm volatile("" ::: "memory");
    }

    // ---- epilogue (C/D: col=lane&15, row=(lane>>4)*4+r) ----
    float*  Cf = (float*)Cv;
    ushort* Cb = (ushort*)Cv;
    #pragma unroll
    for (int m = 0; m < 4; m++) {
        #pragma unroll
        for (int n = 0; n < 4; n++) {
            #pragma unroll
            for (int r = 0; r < 4; r++) {
                int row = m0 + wr * 64 + m * 16 + (lane >> 4) * 4 + r;
                int col = n0 + wc * 64 + n * 16 + (lane & 15);
                float v = acc[m][n][r];
                if (EPI == 1) v = 1.0f / (1.0f + __expf(-v));
                else if (EPI == 2) v = __expf(v);
                size_t idx = (size_t)row * N + col;
                if (OUT_BF) Cb[idx] = f2bf(v);
                else        Cf[idx] = v;
            }
        }
    }
}

// ---------------- scan pass A: per-chunk sums (bf16 in) ----------------
__global__ __launch_bounds__(256)
void scan_partials(const ushort* __restrict__ ke, const ushort* __restrict__ ev,
                   float* __restrict__ pke, float* __restrict__ pkv) {
    const int H = 1024, S = 8192, CHUNK = 32, BH = 4096;
    int h0 = threadIdx.x * 4;
    int c = blockIdx.x;
    int b = blockIdx.y;
    size_t base = ((size_t)b * S + (size_t)c * CHUNK) * H + h0;
    float se0 = 0.f, se1 = 0.f, se2 = 0.f, se3 = 0.f;
    float sv0 = 0.f, sv1 = 0.f, sv2 = 0.f, sv3 = 0.f;
    for (int s = 0; s < CHUNK; s++) {
        ushort4 e4 = *(const ushort4*)(ke + base + (size_t)s * H);
        ushort4 v4 = *(const ushort4*)(ev + base + (size_t)s * H);
        float e0 = bf2f(e4.x), e1 = bf2f(e4.y), e2 = bf2f(e4.z), e3 = bf2f(e4.w);
        se0 += e0; se1 += e1; se2 += e2; se3 += e3;
        sv0 += e0 * bf2f(v4.x); sv1 += e1 * bf2f(v4.y);
        sv2 += e2 * bf2f(v4.z); sv3 += e3 * bf2f(v4.w);
    }
    size_t p = (size_t)c * BH + b * H + h0;
    *(float4*)(pke + p) = make_float4(se0, se1, se2, se3);
    *(float4*)(pkv + p) = make_float4(sv0, sv1, sv2, sv3);
}

// ---------------- scan pass B: exclusive prefix over chunks ----------------
__global__ __launch_bounds__(256)
void scan_offsets(float* __restrict__ pke, float* __restrict__ pkv, int nch, int BH) {
    int i = blockIdx.x * blockDim.x + threadIdx.x;
    if (i >= BH) return;
    float rke = 0.f, rkv = 0.f;
    for (int c = 0; c < nch; c++) {
        size_t idx = (size_t)c * BH + i;
        float a = pke[idx], b = pkv[idx];
        pke[idx] = rke; pkv[idx] = rkv;
        rke += a; rkv += b;
    }
}

// ---------------- scan pass C: inclusive scan + y = sigmoid(emb_q)*(kv/ke) ----------------
__global__ __launch_bounds__(256)
void scan_final(const ushort* __restrict__ ke, const ushort* __restrict__ ev,
                const ushort* __restrict__ sq,
                const float* __restrict__ pke, const float* __restrict__ pkv,
                ushort* __restrict__ ybf) {
    const int H = 1024, S = 8192, CHUNK = 32, BH = 4096;
    int h0 = threadIdx.x * 4;
    int c = blockIdx.x;
    int b = blockIdx.y;
    size_t p = (size_t)c * BH + b * H + h0;
    float4 rke = *(const float4*)(pke + p);
    float4 rkv = *(const float4*)(pkv + p);
    size_t base = ((size_t)b * S + (size_t)c * CHUNK) * H + h0;
    for (int s = 0; s < CHUNK; s++) {
        size_t idx = base + (size_t)s * H;
        ushort4 e4 = *(const ushort4*)(ke + idx);
        ushort4 v4 = *(const ushort4*)(ev + idx);
        ushort4 q4 = *(const ushort4*)(sq + idx);
        float e0 = bf2f(e4.x), e1 = bf2f(e4.y), e2 = bf2f(e4.z), e3 = bf2f(e4.w);
        rke.x += e0; rke.y += e1; rke.z += e2; rke.w += e3;
        rkv.x += e0 * bf2f(v4.x); rkv.y += e1 * bf2f(v4.y);
        rkv.z += e2 * bf2f(v4.z); rkv.w += e3 * bf2f(v4.w);
        ushort4 o;
        o.x = f2bf(bf2f(q4.x) * (rkv.x / rke.x));
        o.y = f2bf(bf2f(q4.y) * (rkv.y / rke.y));
        o.z = f2bf(bf2f(q4.z) * (rkv.z / rke.z));
        o.w = f2bf(bf2f(q4.w) * (rkv.w / rke.w));
        *(ushort4*)(ybf + idx) = o;
    }
}

extern "C" void kernel_launch(void* const* d_in, const int* in_sizes, int n_in,
                              void* d_out, int out_size, void* d_ws, size_t ws_size,
                              hipStream_t stream) {
    const float* q   = (const float*)d_in[0];
    const float* k   = (const float*)d_in[1];
    const float* v   = (const float*)d_in[2];
    const float* w_q = (const float*)d_in[3];
    const float* w_k = (const float*)d_in[4];
    const float* w_v = (const float*)d_in[5];
    const float* w_p = (const float*)d_in[6];
    float* out = (float*)d_out;

    const int B = 4, S = 8192, H = 1024;
    const int M = B * S;                  // 32768
    const size_t MH = (size_t)M * H;      // 33,554,432
    const int NCH = 256;                  // CHUNK = 32
    const int BH = B * H;                 // 4096

    char* ws = (char*)d_ws;
    size_t off = 0;
    auto alloc = [&](size_t bytes) -> char* {
        char* p = ws + off;
        off += (bytes + 255) & ~(size_t)255;
        return p;
    };
    ushort* ybuf = (ushort*)alloc(MH * 2);
    ushort* wqt  = (ushort*)alloc((size_t)H * H * 2);
    ushort* wkt  = (ushort*)alloc((size_t)H * H * 2);
    ushort* wvt  = (ushort*)alloc((size_t)H * H * 2);
    ushort* wpt  = (ushort*)alloc((size_t)H * H * 2);
    ushort* sqb  = (ushort*)alloc(MH * 2);
    ushort* keb  = (ushort*)alloc(MH * 2);
    ushort* evb  = (ushort*)alloc(MH * 2);
    float*  pke  = (float*)alloc((size_t)NCH * BH * 4);
    float*  pkv  = (float*)alloc((size_t)NCH * BH * 4);

    dim3 tg(H / 32, H / 32);
    const int ngg = (M / 128) * (H / 128);   // 2048 blocks, swizzled in-kernel
    dim3 gs(NCH, B);

    transpose_to_bf16<<<tg, 256, 0, stream>>>(w_q, wqt, H, H);
    transpose_to_bf16<<<tg, 256, 0, stream>>>(w_k, wkt, H, H);
    transpose_to_bf16<<<tg, 256, 0, stream>>>(w_v, wvt, H, H);
    transpose_to_bf16<<<tg, 256, 0, stream>>>(w_p, wpt, H, H);

    // projections: fused fp32->bf16 A + epilogue, bf16 outputs
    gemm128<1, 1, 1><<<ngg, 256, 0, stream>>>(q, wqt, sqb);
    gemm128<2, 1, 1><<<ngg, 256, 0, stream>>>(k, wkt, keb);
    gemm128<0, 1, 1><<<ngg, 256, 0, stream>>>(v, wvt, evb);

    // hierarchical scan over S
    scan_partials<<<gs, 256, 0, stream>>>(keb, evb, pke, pkv);
    scan_offsets<<<BH / 256, 256, 0, stream>>>(pke, pkv, NCH, BH);
    scan_final<<<gs, 256, 0, stream>>>(keb, evb, sqb, pke, pkv, ybuf);

    // out = y @ w_p (bf16 A, fp32 out)
    gemm128<0, 0, 0><<<ngg, 256, 0, stream>>>(ybuf, wpt, out);
}

// Round 8
// 584.328 us; speedup vs baseline: 1.1840x; 1.1840x over previous
//
#include <hip/hip_runtime.h>
#include <hip/hip_bf16.h>
#include <cstdint>

#define AS_GLOBAL __attribute__((address_space(1)))
#define AS_LDS    __attribute__((address_space(3)))

typedef __attribute__((ext_vector_type(8))) short bf16x8;
typedef __attribute__((ext_vector_type(8))) unsigned short u16x8;
typedef __attribute__((ext_vector_type(4))) float f32x4;

static __device__ __forceinline__ ushort f2bf(float x) {
    union { float f; uint32_t u; } c;
    c.f = x;
    uint32_t u = c.u;
    u += 0x7fffu + ((u >> 16) & 1u);   // RTNE
    return (ushort)(u >> 16);
}
static __device__ __forceinline__ float bf2f(ushort u) {
    union { uint32_t i; float f; } c;
    c.i = ((uint32_t)u) << 16;
    return c.f;
}

// async global->LDS, 16B/lane. Dest = wave-uniform base + lane*16.
static __device__ __forceinline__ void gload_lds16(const void* g, void* l) {
    __builtin_amdgcn_global_load_lds(
        (const AS_GLOBAL uint32_t*)(uintptr_t)g,
        (AS_LDS uint32_t*)(uint32_t)(uintptr_t)l,
        16, 0, 0);
}

// ---------------- fp32 -> bf16 convert (32B read / 16B write per thread) ----------------
__global__ __launch_bounds__(256)
void cvt_f32_bf16(const float4* __restrict__ in, u16x8* __restrict__ out, int n8) {
    int i = blockIdx.x * 256 + threadIdx.x;
    int stride = gridDim.x * 256;
    for (; i < n8; i += stride) {
        float4 a = in[i * 2], b = in[i * 2 + 1];
        u16x8 o;
        o[0] = f2bf(a.x); o[1] = f2bf(a.y); o[2] = f2bf(a.z); o[3] = f2bf(a.w);
        o[4] = f2bf(b.x); o[5] = f2bf(b.y); o[6] = f2bf(b.z); o[7] = f2bf(b.w);
        out[i] = o;
    }
}

// ---------------- [K,N] fp32 -> [N,K] bf16 transpose ----------------
__global__ __launch_bounds__(256)
void transpose_to_bf16(const float* __restrict__ w, ushort* __restrict__ wt, int K, int N) {
    __shared__ float tile[32][33];
    int bn = blockIdx.x * 32;
    int bk = blockIdx.y * 32;
    int tx = threadIdx.x & 31, ty = threadIdx.x >> 5;
    #pragma unroll
    for (int i = 0; i < 32; i += 8)
        tile[ty + i][tx] = w[(size_t)(bk + ty + i) * N + bn + tx];
    __syncthreads();
    #pragma unroll
    for (int i = 0; i < 32; i += 8)
        wt[(size_t)(bn + ty + i) * K + bk + tx] = f2bf(tile[tx][ty + i]);
}

// =====================================================================
// 128x128 GEMM, 4 waves, BK=32. Both operands via global_load_lds into a
// 3-deep LDS ring staged 2 tiles ahead (counted vmcnt(4), never 0 in-loop).
// XOR-slot bank swizzle on both A and B (pre-swizzled source + XOR'd read).
// One barrier per K-step, lgkmcnt(0) before it (race-safe, r7-verified).
// C[M,1024] = A[M,1024](bf16) * Bt[1024,1024](bf16).
// EPI: 0=none 1=sigmoid 2=exp.  OUT_BF: bf16 C.
// =====================================================================
template<int EPI, int OUT_BF>
__global__ __launch_bounds__(256)
void gemm128(const ushort* __restrict__ A, const ushort* __restrict__ Bt,
             void* __restrict__ Cv) {
    constexpr int K = 1024, N = 1024;
    __shared__ ushort sA[3][128 * 32];     // 3 x 8 KB
    __shared__ ushort sB[3][128 * 32];     // 3 x 8 KB   (48 KB total -> 3 blocks/CU)
    const int tid  = threadIdx.x;
    const int wid  = tid >> 6;
    const int lane = tid & 63;
    const int wr = wid >> 1, wc = wid & 1; // 2x2 waves of 64x64
    const int lr = lane & 15;
    const int kb = lane >> 4;              // logical k-slot 0..3

    // XCD-locality swizzle (r7-verified: FETCH 265->91 MB):
    // 2048 wgs = 8 xcds x 256; one XCD's consecutive locals cycle bn sharing an A-panel.
    const int wg = blockIdx.x;
    const int xcd = wg & 7, local = wg >> 3;
    const int bm = xcd * 32 + (local >> 3);
    const int bn = local & 7;
    const int m0 = bm * 128, n0 = bn * 128;

    f32x4 acc[4][4] = {};

    // ---- staging: 4 gloads/thread (A x2, B x2); source pre-swizzled so that
    // phys 16B-slot p of row r holds logical slot p ^ ((r>>1)&3).
    auto stage = [&](int tile, int buf) {
        const int kt0 = tile * 32;
        ushort* dA = &sA[buf][0];
        ushort* dB = &sB[buf][0];
        #pragma unroll
        for (int j = 0; j < 2; j++) {
            int c = j * 256 + tid;               // 16B chunk id, 512 per operand
            int r = c >> 2, p = c & 3;
            int s = p ^ ((r >> 1) & 3);
            gload_lds16(A  + (size_t)(m0 + r) * K + kt0 + s * 8, dA + c * 8);
            gload_lds16(Bt + (size_t)(n0 + r) * K + kt0 + s * 8, dB + c * 8);
        }
    };
    // ---- compute one BK=32 step; frag reads XOR-deswizzle (2-way banks, free) ----
    auto compute = [&](int buf) {
        const ushort* pA = &sA[buf][0];
        const ushort* pB = &sB[buf][0];
        const int xs = (lr >> 1) & 3;
        bf16x8 af[4], bv[4];
        #pragma unroll
        for (int m = 0; m < 4; m++)
            af[m] = *(const bf16x8*)&pA[(wr * 64 + m * 16 + lr) * 32 + (kb ^ xs) * 8];
        #pragma unroll
        for (int n = 0; n < 4; n++)
            bv[n] = *(const bf16x8*)&pB[(wc * 64 + n * 16 + lr) * 32 + (kb ^ xs) * 8];
        #pragma unroll
        for (int m = 0; m < 4; m++)
            #pragma unroll
            for (int n = 0; n < 4; n++)
                acc[m][n] = __builtin_amdgcn_mfma_f32_16x16x32_bf16(af[m], bv[n], acc[m][n], 0, 0, 0);
    };

    // ---- prologue: stage tiles 0,1 ----
    stage(0, 0);
    stage(1, 1);
    asm volatile("s_waitcnt vmcnt(4)" ::: "memory");   // tile0 done; tile1 in flight
    __builtin_amdgcn_s_barrier();
    asm volatile("" ::: "memory");

    // ---- main loop: 32 K-steps, one barrier each ----
    // queue at step t's wait: [tile(t+1) x4, tile(t+2) x4] -> vmcnt(4) drains t+1.
    // WAR: stage(t+2) overwrites buf read at t-1, whose reads drained at t-1's
    // lgkmcnt(0)+barrier.
    for (int t = 0; t < 32; t++) {
        const int bc = t % 3;
        if (t < 30) stage(t + 2, (t + 2) % 3);
        compute(bc);
        if (t < 30)      asm volatile("s_waitcnt vmcnt(4)" ::: "memory");
        else if (t == 30) asm volatile("s_waitcnt vmcnt(0)" ::: "memory");
        asm volatile("s_waitcnt lgkmcnt(0)" ::: "memory");  // frag reads drained
        __builtin_amdgcn_s_barrier();
        asm volatile("" ::: "memory");
    }

    // ---- epilogue (C/D: col=lane&15, row=(lane>>4)*4+r) ----
    float*  Cf = (float*)Cv;
    ushort* Cb = (ushort*)Cv;
    #pragma unroll
    for (int m = 0; m < 4; m++) {
        #pragma unroll
        for (int n = 0; n < 4; n++) {
            #pragma unroll
            for (int r = 0; r < 4; r++) {
                int row = m0 + wr * 64 + m * 16 + (lane >> 4) * 4 + r;
                int col = n0 + wc * 64 + n * 16 + (lane & 15);
                float v = acc[m][n][r];
                if (EPI == 1) v = 1.0f / (1.0f + __expf(-v));
                else if (EPI == 2) v = __expf(v);
                size_t idx = (size_t)row * N + col;
                if (OUT_BF) Cb[idx] = f2bf(v);
                else        Cf[idx] = v;
            }
        }
    }
}

// ---------------- scan pass A: per-chunk sums (bf16 in, 16B loads) ----------------
// grid (NCH/2, B), 256 threads: tid>>7 selects chunk pair member, 128 threads x 8 h.
__global__ __launch_bounds__(256)
void scan_partials(const ushort* __restrict__ ke, const ushort* __restrict__ ev,
                   float* __restrict__ pke, float* __restrict__ pkv) {
    const int H = 1024, S = 8192, CHUNK = 32, BH = 4096;
    int c  = blockIdx.x * 2 + (threadIdx.x >> 7);
    int h0 = (threadIdx.x & 127) * 8;
    int b  = blockIdx.y;
    size_t base = ((size_t)b * S + (size_t)c * CHUNK) * H + h0;
    float se[8] = {}, sv[8] = {};
    for (int s = 0; s < CHUNK; s++) {
        u16x8 e8 = *(const u16x8*)(ke + base + (size_t)s * H);
        u16x8 v8 = *(const u16x8*)(ev + base + (size_t)s * H);
        #pragma unroll
        for (int i = 0; i < 8; i++) {
            float e = bf2f(e8[i]);
            se[i] += e;
            sv[i] += e * bf2f(v8[i]);
        }
    }
    size_t p = (size_t)c * BH + b * H + h0;
    *(float4*)(pke + p)     = make_float4(se[0], se[1], se[2], se[3]);
    *(float4*)(pke + p + 4) = make_float4(se[4], se[5], se[6], se[7]);
    *(float4*)(pkv + p)     = make_float4(sv[0], sv[1], sv[2], sv[3]);
    *(float4*)(pkv + p + 4) = make_float4(sv[4], sv[5], sv[6], sv[7]);
}

// ---------------- scan pass B: exclusive prefix over chunks ----------------
__global__ __launch_bounds__(256)
void scan_offsets(float* __restrict__ pke, float* __restrict__ pkv, int nch, int BH) {
    int i = blockIdx.x * blockDim.x + threadIdx.x;
    if (i >= BH) return;
    float rke = 0.f, rkv = 0.f;
    for (int c = 0; c < nch; c++) {
        size_t idx = (size_t)c * BH + i;
        float a = pke[idx], b = pkv[idx];
        pke[idx] = rke; pkv[idx] = rkv;
        rke += a; rkv += b;
    }
}

// ---------------- scan pass C: inclusive scan + y = sigmoid(emb_q)*(kv/ke) ----------------
__global__ __launch_bounds__(256)
void scan_final(const ushort* __restrict__ ke, const ushort* __restrict__ ev,
                const ushort* __restrict__ sq,
                const float* __restrict__ pke, const float* __restrict__ pkv,
                ushort* __restrict__ ybf) {
    const int H = 1024, S = 8192, CHUNK = 32, BH = 4096;
    int c  = blockIdx.x * 2 + (threadIdx.x >> 7);
    int h0 = (threadIdx.x & 127) * 8;
    int b  = blockIdx.y;
    size_t p = (size_t)c * BH + b * H + h0;
    float rke[8], rkv[8];
    *(float4*)(rke)     = *(const float4*)(pke + p);
    *(float4*)(rke + 4) = *(const float4*)(pke + p + 4);
    *(float4*)(rkv)     = *(const float4*)(pkv + p);
    *(float4*)(rkv + 4) = *(const float4*)(pkv + p + 4);
    size_t base = ((size_t)b * S + (size_t)c * CHUNK) * H + h0;
    for (int s = 0; s < CHUNK; s++) {
        size_t idx = base + (size_t)s * H;
        u16x8 e8 = *(const u16x8*)(ke + idx);
        u16x8 v8 = *(const u16x8*)(ev + idx);
        u16x8 q8 = *(const u16x8*)(sq + idx);
        u16x8 o;
        #pragma unroll
        for (int i = 0; i < 8; i++) {
            float e = bf2f(e8[i]);
            rke[i] += e;
            rkv[i] += e * bf2f(v8[i]);
            o[i] = f2bf(bf2f(q8[i]) * (rkv[i] / rke[i]));
        }
        *(u16x8*)(ybf + idx) = o;
    }
}

extern "C" void kernel_launch(void* const* d_in, const int* in_sizes, int n_in,
                              void* d_out, int out_size, void* d_ws, size_t ws_size,
                              hipStream_t stream) {
    const float* q   = (const float*)d_in[0];
    const float* k   = (const float*)d_in[1];
    const float* v   = (const float*)d_in[2];
    const float* w_q = (const float*)d_in[3];
    const float* w_k = (const float*)d_in[4];
    const float* w_v = (const float*)d_in[5];
    const float* w_p = (const float*)d_in[6];
    float* out = (float*)d_out;

    const int B = 4, S = 8192, H = 1024;
    const int M = B * S;                  // 32768
    const size_t MH = (size_t)M * H;      // 33,554,432
    const int NCH = 256;                  // CHUNK = 32
    const int BH = B * H;                 // 4096

    char* ws = (char*)d_ws;
    size_t off = 0;
    auto alloc = [&](size_t bytes) -> char* {
        char* p = ws + off;
        off += (bytes + 255) & ~(size_t)255;
        return p;
    };
    ushort* abuf = (ushort*)alloc(MH * 2);     // bf16 staging for q/k/v/y (reused)
    ushort* wqt  = (ushort*)alloc((size_t)H * H * 2);
    ushort* wkt  = (ushort*)alloc((size_t)H * H * 2);
    ushort* wvt  = (ushort*)alloc((size_t)H * H * 2);
    ushort* wpt  = (ushort*)alloc((size_t)H * H * 2);
    ushort* sqb  = (ushort*)alloc(MH * 2);
    ushort* keb  = (ushort*)alloc(MH * 2);
    ushort* evb  = (ushort*)alloc(MH * 2);
    float*  pke  = (float*)alloc((size_t)NCH * BH * 4);
    float*  pkv  = (float*)alloc((size_t)NCH * BH * 4);

    dim3 tg(H / 32, H / 32);
    const int ngg = (M / 128) * (H / 128);   // 2048 blocks, swizzled in-kernel
    dim3 gs(NCH / 2, B);
    const int n8 = (int)(MH / 8);

    transpose_to_bf16<<<tg, 256, 0, stream>>>(w_q, wqt, H, H);
    transpose_to_bf16<<<tg, 256, 0, stream>>>(w_k, wkt, H, H);
    transpose_to_bf16<<<tg, 256, 0, stream>>>(w_v, wvt, H, H);
    transpose_to_bf16<<<tg, 256, 0, stream>>>(w_p, wpt, H, H);

    // sq = sigmoid(q @ w_q)
    cvt_f32_bf16<<<2048, 256, 0, stream>>>((const float4*)q, (u16x8*)abuf, n8);
    gemm128<1, 1><<<ngg, 256, 0, stream>>>(abuf, wqt, sqb);
    // ke = exp(k @ w_k)
    cvt_f32_bf16<<<2048, 256, 0, stream>>>((const float4*)k, (u16x8*)abuf, n8);
    gemm128<2, 1><<<ngg, 256, 0, stream>>>(abuf, wkt, keb);
    // ev = v @ w_v
    cvt_f32_bf16<<<2048, 256, 0, stream>>>((const float4*)v, (u16x8*)abuf, n8);
    gemm128<0, 1><<<ngg, 256, 0, stream>>>(abuf, wvt, evb);

    // hierarchical scan over S
    scan_partials<<<gs, 256, 0, stream>>>(keb, evb, pke, pkv);
    scan_offsets<<<BH / 256, 256, 0, stream>>>(pke, pkv, NCH, BH);
    scan_final<<<gs, 256, 0, stream>>>(keb, evb, sqb, pke, pkv, abuf);

    // out = y @ w_p (fp32 out)
    gemm128<0, 0><<<ngg, 256, 0, stream>>>(abuf, wpt, out);
}